// Round 1
// baseline (355.351 us; speedup 1.0000x reference)
//
#include <hip/hip_runtime.h>
#include <hip/hip_bf16.h>

// Problem: B=2048, D=256, K=256, NC=64, F=512.
// Restructure: only Q[b,c] = sum_k q[b,k] cq[c,k] is needed (NC=64), so
//   Q2[b,c] = z^T M_c z,  M_c = sum_k cq[c,k] Gamma_k  (precomputed, bf16)
//   Qlin[b,c] = z . WzT[:,c] + f . WfT[:,c] + beff[c]
// Heavy GEMM (M=2048,N=64,P=65536) done with mfma_f32_16x16x32_bf16,
// A[b,p]=z_i*z_j generated in registers, B staged in padded LDS.

#define B_SZ 2048
#define D_SZ 256
#define K_SZ 256
#define NC_SZ 64
#define F_SZ 512
#define P_SZ 65536

typedef short  short8  __attribute__((ext_vector_type(8)));
typedef float  floatx4 __attribute__((ext_vector_type(4)));
typedef int    intx4   __attribute__((ext_vector_type(4)));

// ws layout (float offsets)
#define WS_WZT   0        // 256*64 f32
#define WS_WFT   16384    // 512*64 f32
#define WS_BEFF  49152    // 64 f32
#define WS_CQT   50176    // 256*64 f32  (cqT[k*64+c] = cq[c*256+k])
#define WS_Q2    66560    // 2048*64 f32
#define WS_MBF   197632   // bf16[64*65536] starts here

__device__ __forceinline__ short f2bf_s(float x) {
    __hip_bfloat16 h = __float2bfloat16(x);
    return *reinterpret_cast<short*>(&h);
}

// ---------------- K1: collapse weights ----------------
__global__ __launch_bounds__(64) void prep_kernel(
        const float* __restrict__ Wqz, const float* __restrict__ bqz,
        const float* __restrict__ Wqf, const float* __restrict__ bqf,
        const float* __restrict__ cq,  float* __restrict__ ws) {
    const int c = threadIdx.x;  // 0..63
    const int bid = blockIdx.x;
    if (bid < 256) {
        const int i = bid;
        float acc = 0.f;
        for (int k = 0; k < K_SZ; ++k)
            acc = fmaf(cq[c*K_SZ + k], Wqz[k*D_SZ + i], acc);
        ws[WS_WZT + i*64 + c] = acc;
        ws[WS_CQT + i*64 + c] = cq[c*K_SZ + i];
    } else if (bid < 768) {
        const int j = bid - 256;
        float acc = 0.f;
        for (int k = 0; k < K_SZ; ++k)
            acc = fmaf(cq[c*K_SZ + k], Wqf[k*F_SZ + j], acc);
        ws[WS_WFT + j*64 + c] = acc;
    } else {
        float acc = 0.f;
        for (int k = 0; k < K_SZ; ++k)
            acc = fmaf(cq[c*K_SZ + k], bqz[k] + bqf[k], acc);
        ws[WS_BEFF + c] = acc;
    }
}

// ---------------- K2: M_c = sum_k cq[c,k] Gamma_k  (bf16 out) ----------------
__global__ __launch_bounds__(256) void mc_kernel(
        const float* __restrict__ gamma, const float* __restrict__ cqT,
        __hip_bfloat16* __restrict__ mbf) {
    const int p = blockIdx.x * 256 + threadIdx.x;
    float acc[NC_SZ];
    #pragma unroll
    for (int c = 0; c < NC_SZ; ++c) acc[c] = 0.f;

    float gcur[4];
    #pragma unroll
    for (int u = 0; u < 4; ++u) gcur[u] = gamma[u*P_SZ + p];

    for (int k4 = 0; k4 < K_SZ; k4 += 4) {
        float gnx[4];
        #pragma unroll
        for (int u = 0; u < 4; ++u) {
            int kn = k4 + 4 + u; if (kn > K_SZ-1) kn = K_SZ-1;
            gnx[u] = gamma[kn*P_SZ + p];
        }
        #pragma unroll
        for (int u = 0; u < 4; ++u) {
            const float* __restrict__ cqk = cqT + (k4 + u)*64;  // wave-uniform -> s_loads
            const float g = gcur[u];
            #pragma unroll
            for (int c = 0; c < NC_SZ; ++c) acc[c] = fmaf(cqk[c], g, acc[c]);
        }
        #pragma unroll
        for (int u = 0; u < 4; ++u) gcur[u] = gnx[u];
    }
    #pragma unroll
    for (int c = 0; c < NC_SZ; ++c)
        mbf[c*P_SZ + p] = __float2bfloat16(acc[c]);
}

// ---------------- K4: Q2[b,c] += sum_p (z_i z_j) M_c[p]  (MFMA bf16) ----------------
// grid (32, 16): x = b-tile of 64, y = i-range of 16 rows (split-P, atomic accum)
__global__ __launch_bounds__(256, 2) void qf_kernel(
        const float* __restrict__ z, const __hip_bfloat16* __restrict__ mbf,
        float* __restrict__ q2) {
    __shared__ __align__(16) char bt[64 * 528];   // 64 c-rows x 256 bf16, padded to 528B (2-way LDS conflicts only)
    const int tid  = threadIdx.x;
    const int w    = tid >> 6;        // wave 0..3
    const int lane = tid & 63;
    const int ln   = lane & 15;       // m (b) / n (c) index
    const int lq   = lane >> 4;       // quad 0..3
    const int b0   = blockIdx.x * 64;
    const int i0   = blockIdx.y * 16;
    const int bb   = b0 + w*16 + ln;  // this lane's b-row (A operand m)

    // preload z_j in f32: zj[g][jj], j = g*32 + lq*8 + jj  (full 256-row)
    float zj[8][8];
    #pragma unroll
    for (int g = 0; g < 8; ++g) {
        const floatx4* zp = (const floatx4*)(z + bb*D_SZ + g*32 + lq*8);
        floatx4 a = zp[0], b4 = zp[1];
        #pragma unroll
        for (int t = 0; t < 4; ++t) { zj[g][t] = a[t]; zj[g][4+t] = b4[t]; }
    }
    // preload z_i for the 16 i-rows of this block
    float ziv[16];
    {
        const floatx4* zp = (const floatx4*)(z + bb*D_SZ + i0);
        #pragma unroll
        for (int t = 0; t < 4; ++t) {
            floatx4 v = zp[t];
            #pragma unroll
            for (int u = 0; u < 4; ++u) ziv[4*t + u] = v[u];
        }
    }

    floatx4 acc[4] = {{0.f,0.f,0.f,0.f},{0.f,0.f,0.f,0.f},{0.f,0.f,0.f,0.f},{0.f,0.f,0.f,0.f}};

    for (int il = 0; il < 16; ++il) {
        const int i = i0 + il;
        // stage B-tile: Mbf[c][i*256 + j] -> bt[c][j], 2048 16B-chunks over 256 threads
        #pragma unroll
        for (int s = 0; s < 8; ++s) {
            const int e  = s*256 + tid;
            const int c  = e >> 5;          // c-row
            const int jc = e & 31;          // 16B chunk within row
            intx4 v = *(const intx4*)((const char*)mbf + ((size_t)c*P_SZ + (size_t)i*256 + jc*8)*2);
            *(intx4*)(bt + c*528 + jc*16) = v;
        }
        __syncthreads();

        const float zi = ziv[il];
        #pragma unroll
        for (int g = 0; g < 8; ++g) {
            short8 af;
            #pragma unroll
            for (int jj = 0; jj < 8; ++jj) af[jj] = f2bf_s(zi * zj[g][jj]);
            #pragma unroll
            for (int cf = 0; cf < 4; ++cf) {
                short8 bf = *(const short8*)(bt + (cf*16 + ln)*528 + (g*32 + lq*8)*2);
                acc[cf] = __builtin_amdgcn_mfma_f32_16x16x32_bf16(af, bf, acc[cf], 0, 0, 0);
            }
        }
        __syncthreads();
    }

    // C/D layout: col = lane&15, row = (lane>>4)*4 + reg  [m89-verified]
    #pragma unroll
    for (int cf = 0; cf < 4; ++cf) {
        #pragma unroll
        for (int r = 0; r < 4; ++r) {
            const int brow = b0 + w*16 + lq*4 + r;
            atomicAdd(q2 + brow*NC_SZ + cf*16 + ln, acc[cf][r]);
        }
    }
}

// ---------------- K5: assemble scores, softmax, argmax ----------------
__global__ __launch_bounds__(64) void final_kernel(
        const float* __restrict__ z, const float* __restrict__ feat,
        const float* __restrict__ ws, float* __restrict__ out) {
    const int b = blockIdx.x;
    const int c = threadIdx.x;  // 0..63 (one wave per b-row)
    const float* __restrict__ wzT  = ws + WS_WZT;
    const float* __restrict__ wfT  = ws + WS_WFT;
    const float* __restrict__ beff = ws + WS_BEFF;
    const float* __restrict__ cqT  = ws + WS_CQT;
    const float* __restrict__ q2   = ws + WS_Q2;

    float qlin = beff[c];
    float r2 = 0.f, csq = 0.f, dsq = 0.f;
    const float* __restrict__ zr = z + b*D_SZ;
    #pragma unroll 4
    for (int i = 0; i < D_SZ; ++i) {
        const float zi = zr[i];             // wave-uniform -> scalar load
        const float cc = cqT[i*64 + c];     // coalesced
        qlin = fmaf(zi, wzT[i*64 + c], qlin);
        const float d = zi - cc;
        dsq = fmaf(d, d, dsq);
        csq = fmaf(cc, cc, csq);
        r2  = fmaf(zi, zi, r2);
    }
    const float* __restrict__ fr = feat + b*F_SZ;
    #pragma unroll 4
    for (int j = 0; j < F_SZ; ++j)
        qlin = fmaf(fr[j], wfT[j*64 + c], qlin);

    const float Q = qlin + q2[b*NC_SZ + c];

    // score assembly in f64 (cheap; maximizes argmax fidelity)
    const double r2d = (double)r2, csqd = (double)csq, dsqd = (double)dsq;
    const double denom = (1.0 - r2d) * (1.0 - csqd);
    double arg = 1.0 + 2.0 * dsqd / (denom + 0.001);
    if (arg < 1.001) arg = 1.001;
    const double dist = acosh(arg);
    double tmp = 1.0 - r2d; if (tmp < 0.001) tmp = 0.001;
    double tau = 8.0 * tmp;  // sqrt(256)*0.5 = 8
    if (tau < 0.01) tau = 0.01;
    double r2c = r2d; if (r2c > 0.999) r2c = 0.999;
    const double lam = 2.0 / (1.0 - r2c + 0.001);
    const double score = -dist / tau + 0.1 * ((double)Q / lam) / tau;

    // softmax over 64 lanes
    double m = score;
    #pragma unroll
    for (int off = 32; off > 0; off >>= 1) {
        double o = __shfl_xor(m, off, 64);
        m = fmax(m, o);
    }
    const double e = exp(score - m);
    double s = e;
    #pragma unroll
    for (int off = 32; off > 0; off >>= 1) s += __shfl_xor(s, off, 64);
    out[b*NC_SZ + c] = (float)(e / s);

    // argmax (first-index tie-break, matches jnp.argmax)
    double bsc = score; int bix = c;
    #pragma unroll
    for (int off = 32; off > 0; off >>= 1) {
        double osc = __shfl_xor(bsc, off, 64);
        int    oix = __shfl_xor(bix, off, 64);
        if (osc > bsc || (osc == bsc && oix < bix)) { bsc = osc; bix = oix; }
    }
    if (c == 0) out[B_SZ*NC_SZ + b] = (float)bix;
}

extern "C" void kernel_launch(void* const* d_in, const int* in_sizes, int n_in,
                              void* d_out, int out_size, void* d_ws, size_t ws_size,
                              hipStream_t stream) {
    const float* z    = (const float*)d_in[0];
    const float* feat = (const float*)d_in[1];
    const float* Wqz  = (const float*)d_in[2];
    const float* bqz  = (const float*)d_in[3];
    const float* Wqf  = (const float*)d_in[4];
    const float* bqf  = (const float*)d_in[5];
    const float* gamma= (const float*)d_in[6];
    const float* cq   = (const float*)d_in[7];
    float* out = (float*)d_out;
    float* ws  = (float*)d_ws;
    __hip_bfloat16* mbf = (__hip_bfloat16*)(ws + WS_MBF);

    prep_kernel<<<769, 64, 0, stream>>>(Wqz, bqz, Wqf, bqf, cq, ws);
    mc_kernel<<<256, 256, 0, stream>>>(gamma, ws + WS_CQT, mbf);
    hipMemsetAsync(ws + WS_Q2, 0, (size_t)B_SZ*NC_SZ*sizeof(float), stream);
    qf_kernel<<<dim3(32, 16), 256, 0, stream>>>(z, mbf, ws + WS_Q2);
    final_kernel<<<B_SZ, 64, 0, stream>>>(z, feat, ws, out);
}

// Round 2
// 283.650 us; speedup vs baseline: 1.2528x; 1.2528x over previous
//
#include <hip/hip_runtime.h>
#include <hip/hip_bf16.h>

// B=2048, D=256, K=256, NC=64, F=512.
// Q[b,c] = Qlin[b,c] + z^T M_c z, M_c = sum_k cq[c,k] Gamma_k (bf16, 8MB).
// Kernels: prep (collapse weights) -> mc (M_c, VALU c-split x4) ->
// memset Q2 -> lin (qlin atomic GEMM) -> qf (MFMA 32x32x16, split-i atomic)
// -> final (dot/r2 + f64 score + softmax/argmax).

#define B_SZ 2048
#define D_SZ 256
#define K_SZ 256
#define NC_SZ 64
#define F_SZ 512
#define P_SZ 65536

typedef short  short8   __attribute__((ext_vector_type(8)));
typedef float  floatx4  __attribute__((ext_vector_type(4)));
typedef float  floatx16 __attribute__((ext_vector_type(16)));

// ws layout (float offsets); total 196736 f32 + 8 MB bf16 = 9.18 MB (== R1 footprint)
#define WS_WZT   0        // 256*64
#define WS_WFT   16384    // 512*64
#define WS_BEFF  49152    // 64
#define WS_CSQ   49216    // 64
#define WS_CQT   49280    // 256*64  cqT[i*64+c] = cq[c*256+i]
#define WS_Q2    65664    // 2048*64 (atomic accum: lin + qf)
#define WS_MBF   196736   // bf16[64*65536]

__device__ __forceinline__ short f2bf_s(float x) {
    __hip_bfloat16 h = __float2bfloat16(x);
    return *reinterpret_cast<short*>(&h);
}

// ---------------- prep: collapsed weights, cqT, beff, csq ----------------
__global__ __launch_bounds__(256) void prep_kernel(
        const float* __restrict__ Wqz, const float* __restrict__ bqz,
        const float* __restrict__ Wqf, const float* __restrict__ bqf,
        const float* __restrict__ cq,  float* __restrict__ ws) {
    const int w = threadIdx.x >> 6, c = threadIdx.x & 63;
    const int bid = blockIdx.x;
    if (bid < 64) {
        const int i = bid*4 + w;
        float acc = 0.f;
        #pragma unroll 4
        for (int k = 0; k < K_SZ; ++k)
            acc = fmaf(cq[c*K_SZ + k], Wqz[k*D_SZ + i], acc);
        ws[WS_WZT + i*64 + c] = acc;
        ws[WS_CQT + i*64 + c] = cq[c*K_SZ + i];
    } else if (bid < 192) {
        const int j = (bid - 64)*4 + w;
        float acc = 0.f;
        #pragma unroll 4
        for (int k = 0; k < K_SZ; ++k)
            acc = fmaf(cq[c*K_SZ + k], Wqf[k*F_SZ + j], acc);
        ws[WS_WFT + j*64 + c] = acc;
    } else {
        if (w == 0) {
            float acc = 0.f;
            for (int k = 0; k < K_SZ; ++k)
                acc = fmaf(cq[c*K_SZ + k], bqz[k] + bqf[k], acc);
            ws[WS_BEFF + c] = acc;
        } else if (w == 1) {
            float acc = 0.f;
            for (int i = 0; i < D_SZ; ++i) {
                const float v = cq[c*K_SZ + i];
                acc = fmaf(v, v, acc);
            }
            ws[WS_CSQ + c] = acc;
        }
    }
}

// ---------------- mc: M_c = sum_k cq[c,k] Gamma_k, c-split x4 ----------------
// grid (4, 256): x = c-group (fast dim -> adjacent blocks share Gamma lines in L2/L3)
__global__ __launch_bounds__(256, 4) void mc_kernel(
        const float* __restrict__ gamma, const float* __restrict__ cqT,
        __hip_bfloat16* __restrict__ mbf) {
    const int cb = blockIdx.x * 16;
    const int p  = blockIdx.y * 256 + threadIdx.x;
    float acc[16];
    #pragma unroll
    for (int j = 0; j < 16; ++j) acc[j] = 0.f;

    float g[8];
    #pragma unroll
    for (int u = 0; u < 8; ++u) g[u] = gamma[(size_t)u*P_SZ + p];

    for (int k0 = 0; k0 < K_SZ; k0 += 8) {
        float gn[8];
        #pragma unroll
        for (int u = 0; u < 8; ++u) {
            int kn = k0 + 8 + u; if (kn > K_SZ-1) kn = K_SZ-1;
            gn[u] = gamma[(size_t)kn*P_SZ + p];
        }
        #pragma unroll
        for (int u = 0; u < 8; ++u) {
            const float* __restrict__ cqk = cqT + (k0 + u)*64 + cb;  // wave-uniform
            const float gv = g[u];
            #pragma unroll
            for (int j = 0; j < 16; ++j) acc[j] = fmaf(cqk[j], gv, acc[j]);
        }
        #pragma unroll
        for (int u = 0; u < 8; ++u) g[u] = gn[u];
    }
    #pragma unroll
    for (int j = 0; j < 16; ++j)
        mbf[(size_t)(cb + j)*P_SZ + p] = __float2bfloat16(acc[j]);
}

// ---------------- lin: qlin atomic GEMM (2 b-rows/wave, i/f halved) ----------
__global__ __launch_bounds__(256) void lin_kernel(
        const float* __restrict__ z, const float* __restrict__ feat,
        const float* __restrict__ ws, float* __restrict__ q2) {
    const int w = threadIdx.x >> 6, c = threadIdx.x & 63;
    const int half = blockIdx.x & 1, bp = blockIdx.x >> 1;
    const int b0 = bp*8 + w*2;
    const float* __restrict__ wzT = ws + WS_WZT + half*128*64;
    const float* __restrict__ wfT = ws + WS_WFT + half*256*64;
    const float* __restrict__ z0 = z + b0*D_SZ + half*128;
    const float* __restrict__ z1 = z0 + D_SZ;
    float q0 = 0.f, q1 = 0.f;
    #pragma unroll 4
    for (int i = 0; i < 128; ++i) {
        const float wv = wzT[i*64 + c];
        q0 = fmaf(z0[i], wv, q0);
        q1 = fmaf(z1[i], wv, q1);
    }
    const float* __restrict__ f0 = feat + b0*F_SZ + half*256;
    const float* __restrict__ f1 = f0 + F_SZ;
    #pragma unroll 4
    for (int j = 0; j < 256; ++j) {
        const float wv = wfT[j*64 + c];
        q0 = fmaf(f0[j], wv, q0);
        q1 = fmaf(f1[j], wv, q1);
    }
    atomicAdd(q2 + b0*64 + c, q0);
    atomicAdd(q2 + (b0 + 1)*64 + c, q1);
}

// ---------------- qf: Q2 via mfma_f32_32x32x16_bf16 -------------------------
// grid (16, 32): x = b-tile of 128 (fast dim shares mbf i-slice), y = i-group of 8
__global__ __launch_bounds__(256, 2) void qf_kernel(
        const float* __restrict__ z, const __hip_bfloat16* __restrict__ mbf,
        float* __restrict__ q2) {
    __shared__ __align__(16) char bt[64 * 512];   // XOR-swizzled, conflict-free
    const int tid  = threadIdx.x;
    const int w    = tid >> 6;
    const int lane = tid & 63;
    const int ln   = lane & 31;
    const int half = lane >> 5;
    const int b0   = blockIdx.x * 128;
    const int i0   = blockIdx.y * 8;
    const int bb   = b0 + w*32 + ln;     // A-operand m-row

    // zj: j = ch*16 + half*8 + kk, ch 0..15, kk 0..7  (128 f32)
    floatx4 zj[16][2];
    #pragma unroll
    for (int ch = 0; ch < 16; ++ch) {
        const floatx4* zp = (const floatx4*)(z + bb*D_SZ + ch*16 + half*8);
        zj[ch][0] = zp[0]; zj[ch][1] = zp[1];
    }
    float ziv[8];
    {
        const floatx4* zp = (const floatx4*)(z + bb*D_SZ + i0);
        floatx4 a = zp[0], b4 = zp[1];
        #pragma unroll
        for (int t = 0; t < 4; ++t) { ziv[t] = a[t]; ziv[4+t] = b4[t]; }
    }

    floatx16 acc0, acc1;
    #pragma unroll
    for (int r = 0; r < 16; ++r) { acc0[r] = 0.f; acc1[r] = 0.f; }

    for (int il = 0; il < 8; ++il) {
        const int i = i0 + il;
        // stage M rows: 64 c x 256 j bf16 = 32 KB, swizzled 16B chunks
        #pragma unroll
        for (int s = 0; s < 8; ++s) {
            const int e  = s*256 + tid;
            const int cr = e >> 5, jc = e & 31;
            short8 v = *(const short8*)((const char*)mbf +
                        ((size_t)cr*P_SZ + (size_t)i*256 + jc*8)*2);
            *(short8*)(bt + cr*512 + ((jc ^ (cr & 31)) << 4)) = v;
        }
        __syncthreads();

        const float zi = ziv[il];
        #pragma unroll
        for (int ch = 0; ch < 16; ++ch) {
            short8 af;
            #pragma unroll
            for (int kk = 0; kk < 4; ++kk) {
                af[kk]     = f2bf_s(zi * zj[ch][0][kk]);
                af[4 + kk] = f2bf_s(zi * zj[ch][1][kk]);
            }
            const int fc = ch*2 + half;
            const int r0 = ln, r1 = 32 + ln;
            short8 bf0 = *(const short8*)(bt + r0*512 + ((fc ^ ln) << 4));
            short8 bf1 = *(const short8*)(bt + r1*512 + ((fc ^ ln) << 4));
            acc0 = __builtin_amdgcn_mfma_f32_32x32x16_bf16(af, bf0, acc0, 0, 0, 0);
            acc1 = __builtin_amdgcn_mfma_f32_32x32x16_bf16(af, bf1, acc1, 0, 0, 0);
        }
        __syncthreads();
    }

    // C/D: col = lane&31, row = (reg&3) + 8*(reg>>2) + 4*(lane>>5)  [m74/m101]
    #pragma unroll
    for (int r = 0; r < 16; ++r) {
        const int row  = (r & 3) + 8*(r >> 2) + 4*half;
        const int brow = b0 + w*32 + row;
        atomicAdd(q2 + brow*NC_SZ + ln,      acc0[r]);
        atomicAdd(q2 + brow*NC_SZ + 32 + ln, acc1[r]);
    }
}

// ---------------- final: dot/r2 + f64 score + softmax/argmax ----------------
__global__ __launch_bounds__(256) void final_kernel(
        const float* __restrict__ z, const float* __restrict__ ws,
        float* __restrict__ out) {
    const int w = threadIdx.x >> 6, c = threadIdx.x & 63;
    const int b = blockIdx.x*4 + w;
    const float* __restrict__ zr  = z + b*D_SZ;
    const float* __restrict__ cqT = ws + WS_CQT;

    float dot = 0.f, r2 = 0.f;
    #pragma unroll 4
    for (int i = 0; i < D_SZ; ++i) {
        const float zi = zr[i];                 // wave-uniform -> scalar
        dot = fmaf(zi, cqT[i*64 + c], dot);     // coalesced
        r2  = fmaf(zi, zi, r2);
    }
    const float Q   = ws[WS_Q2 + b*64 + c] + ws[WS_BEFF + c];
    const float csq = ws[WS_CSQ + c];
    const float dsq = fmaf(-2.f, dot, r2) + csq;

    const double r2d = (double)r2, csqd = (double)csq, dsqd = (double)dsq;
    const double denom = (1.0 - r2d) * (1.0 - csqd);
    double arg = 1.0 + 2.0 * dsqd / (denom + 0.001);
    if (arg < 1.001) arg = 1.001;
    const double dist = acosh(arg);
    double tmp = 1.0 - r2d; if (tmp < 0.001) tmp = 0.001;
    double tau = 8.0 * tmp;  // sqrt(256)*0.5
    if (tau < 0.01) tau = 0.01;
    double r2c = r2d; if (r2c > 0.999) r2c = 0.999;
    const double lam = 2.0 / (1.0 - r2c + 0.001);
    const double score = -dist / tau + 0.1 * ((double)Q / lam) / tau;

    double m = score;
    #pragma unroll
    for (int off = 32; off > 0; off >>= 1) {
        double o = __shfl_xor(m, off, 64);
        m = fmax(m, o);
    }
    const double e = exp(score - m);
    double s = e;
    #pragma unroll
    for (int off = 32; off > 0; off >>= 1) s += __shfl_xor(s, off, 64);
    out[b*NC_SZ + c] = (float)(e / s);

    double bsc = score; int bix = c;
    #pragma unroll
    for (int off = 32; off > 0; off >>= 1) {
        double osc = __shfl_xor(bsc, off, 64);
        int    oix = __shfl_xor(bix, off, 64);
        if (osc > bsc || (osc == bsc && oix < bix)) { bsc = osc; bix = oix; }
    }
    if (c == 0) out[B_SZ*NC_SZ + b] = (float)bix;
}

extern "C" void kernel_launch(void* const* d_in, const int* in_sizes, int n_in,
                              void* d_out, int out_size, void* d_ws, size_t ws_size,
                              hipStream_t stream) {
    const float* z    = (const float*)d_in[0];
    const float* feat = (const float*)d_in[1];
    const float* Wqz  = (const float*)d_in[2];
    const float* bqz  = (const float*)d_in[3];
    const float* Wqf  = (const float*)d_in[4];
    const float* bqf  = (const float*)d_in[5];
    const float* gamma= (const float*)d_in[6];
    const float* cq   = (const float*)d_in[7];
    float* out = (float*)d_out;
    float* ws  = (float*)d_ws;
    __hip_bfloat16* mbf = (__hip_bfloat16*)(ws + WS_MBF);

    prep_kernel<<<193, 256, 0, stream>>>(Wqz, bqz, Wqf, bqf, cq, ws);
    mc_kernel<<<dim3(4, 256), 256, 0, stream>>>(gamma, ws + WS_CQT, mbf);
    hipMemsetAsync(ws + WS_Q2, 0, (size_t)B_SZ*NC_SZ*sizeof(float), stream);
    lin_kernel<<<512, 256, 0, stream>>>(z, feat, ws, ws + WS_Q2);
    qf_kernel<<<dim3(16, 32), 256, 0, stream>>>(z, mbf, ws + WS_Q2);
    final_kernel<<<512, 256, 0, stream>>>(z, ws, out);
}